// Round 3
// baseline (382.935 us; speedup 1.0000x reference)
//
#include <hip/hip_runtime.h>
#include <math.h>

#define BB 64
#define SS 512
#define HH 768
#define LL 21

// ws layout (floats):
//   em    : [0, BB*SS*LL)               emissions f32
//   num   : BB*SS*LL + [0,64)           numerator per batch
//   denom : +64                         denominator per batch
//   tags  : int32 area after            decoded tags (BB*SS)

// ---------------- K1: emissions = hidden @ W + b ----------------
// wave-per-row; Wt (transposed W) in LDS; lane-split over K; butterfly reduce.
__global__ __launch_bounds__(256) void k_emis(const float* __restrict__ hidden,
                                              const float* __restrict__ W,
                                              const float* __restrict__ bias,
                                              float* __restrict__ em) {
    __shared__ __align__(16) float Wt[LL * HH];
    int tid = threadIdx.x;
    for (int idx = tid; idx < HH * LL; idx += 256) {
        int k = idx / LL, l = idx % LL;       // W is [HH][LL] row-major
        Wt[l * HH + k] = W[idx];
    }
    __syncthreads();

    int lane = tid & 63, wid = tid >> 6;
    float bl = (lane < LL) ? bias[lane] : 0.f;

    int gw = blockIdx.x * 4 + wid;
    int nw = gridDim.x * 4;
    for (int row = gw; row < BB * SS; row += nw) {
        const float4* hp = (const float4*)(hidden + (size_t)row * HH);
        float4 h0 = hp[lane];
        float4 h1 = hp[lane + 64];
        float4 h2 = hp[lane + 128];
        float out = 0.f;
        #pragma unroll
        for (int l = 0; l < LL; ++l) {
            const float4* wp = (const float4*)(Wt + l * HH);
            float4 w0 = wp[lane];
            float4 w1 = wp[lane + 64];
            float4 w2 = wp[lane + 128];
            float p;
            p = h0.x * w0.x;
            p = fmaf(h0.y, w0.y, p); p = fmaf(h0.z, w0.z, p); p = fmaf(h0.w, w0.w, p);
            p = fmaf(h1.x, w1.x, p); p = fmaf(h1.y, w1.y, p);
            p = fmaf(h1.z, w1.z, p); p = fmaf(h1.w, w1.w, p);
            p = fmaf(h2.x, w2.x, p); p = fmaf(h2.y, w2.y, p);
            p = fmaf(h2.z, w2.z, p); p = fmaf(h2.w, w2.w, p);
            #pragma unroll
            for (int off = 32; off; off >>= 1) p += __shfl_xor(p, off);
            if (lane == l) out = p;
        }
        if (lane < LL) em[(size_t)row * LL + lane] = out + bl;
    }
}

// ---------------- K2: CRF numerator per batch ----------------
__global__ __launch_bounds__(512) void k_num(const float* __restrict__ em,
                                             const int* __restrict__ attn,
                                             const int* __restrict__ labels,
                                             const float* __restrict__ startT,
                                             const float* __restrict__ endT,
                                             const float* __restrict__ trans,
                                             float* __restrict__ num) {
    int b = blockIdx.x, t = threadIdx.x;
    __shared__ int   stag[SS];
    __shared__ float sred[SS];
    __shared__ int   scnt[SS];

    int lab = labels[b * SS + t];
    int mk  = attn[b * SS + t];
    int tag = (lab < 0) ? 0 : lab;
    if (t == 0) tag = 0;
    int valid = (mk != 0 && lab >= 0) ? 1 : 0;
    if (t == 0) valid = 1;
    stag[t] = tag;
    __syncthreads();

    float term = 0.f;
    if (t > 0 && valid) {
        int pt = stag[t - 1];
        term = trans[pt * LL + tag] + em[((size_t)b * SS + t) * LL + tag];
    }
    sred[t] = term;
    scnt[t] = valid;
    __syncthreads();
    for (int off = 256; off; off >>= 1) {
        if (t < off) { sred[t] += sred[t + off]; scnt[t] += scnt[t + off]; }
        __syncthreads();
    }
    if (t == 0) {
        int cnt   = scnt[0];
        int lastt = stag[cnt - 1];
        int t0    = stag[0];
        num[b] = startT[t0] + em[(size_t)b * SS * LL + t0] + endT[lastt] + sred[0];
    }
}

// ---------------- K3: Viterbi (blocks 0..63) + logsumexp scan (blocks 64..127) ----------------
// one wave (64 threads) per chain; lane j<21 owns state j; trans column in regs;
// cross-lane state broadcast via readlane with unrolled constant index.
__global__ __launch_bounds__(64) void k_scan(const float* __restrict__ em,
                                             const int* __restrict__ attn,
                                             const float* __restrict__ startT,
                                             const float* __restrict__ endT,
                                             const float* __restrict__ trans,
                                             float* __restrict__ denom,
                                             int* __restrict__ tagsOut) {
    __shared__ unsigned char hist[(SS - 1) * LL];
    __shared__ short tg[SS];
    __shared__ unsigned char mks[SS];

    int lane = threadIdx.x;
    int b = blockIdx.x & 63;
    bool isVit = blockIdx.x < 64;

    float Tc[LL];
    #pragma unroll
    for (int i = 0; i < LL; ++i) Tc[i] = (lane < LL) ? trans[i * LL + lane] : 0.f;

    const float* emb = em + (size_t)b * SS * LL;
    const int* mrow = attn + b * SS;

    float a = ((lane < LL) ? startT[lane] : -INFINITY) + ((lane < LL) ? emb[lane] : 0.f);

    if (isVit) {
        for (int t = 1; t < SS; ++t) {
            float emit = (lane < LL) ? emb[t * LL + lane] : 0.f;
            int mt = mrow[t];
            if (lane == 0) mks[t] = (unsigned char)(mt != 0);
            float best = -INFINITY; int bi = 0;
            #pragma unroll
            for (int i = 0; i < LL; ++i) {
                float ai = __int_as_float(__builtin_amdgcn_readlane(__float_as_int(a), i));
                float c = ai + Tc[i];
                bool g = c > best;          // strict > : first max wins (matches argmax)
                best = g ? c : best;
                bi   = g ? i : bi;
            }
            if (lane < LL) hist[(t - 1) * LL + lane] = (unsigned char)bi;
            float anew = best + emit;
            a = (mt && lane < LL) ? anew : a;
        }
        // final argmax over states (first max wins)
        float f = (lane < LL) ? a + endT[lane] : -INFINITY;
        float m = f;
        #pragma unroll
        for (int off = 32; off; off >>= 1) m = fmaxf(m, __shfl_xor(m, off));
        unsigned long long msk = __ballot(f == m);
        int cur = __ffsll(msk) - 1;
        __syncthreads();
        if (lane == 0) {
            for (int t = SS - 1; t >= 1; --t) {
                tg[t] = (short)cur;
                int prev = hist[(t - 1) * LL + cur];
                cur = mks[t] ? prev : cur;
            }
            tg[0] = (short)cur;
        }
        __syncthreads();
        for (int t = lane; t < SS; t += 64) tagsOut[b * SS + t] = (int)tg[t];
    } else {
        for (int t = 1; t < SS; ++t) {
            float emit = (lane < LL) ? emb[t * LL + lane] : 0.f;
            int mt = mrow[t];
            float c[LL];
            float m = -INFINITY;
            #pragma unroll
            for (int i = 0; i < LL; ++i) {
                float ai = __int_as_float(__builtin_amdgcn_readlane(__float_as_int(a), i));
                c[i] = ai + Tc[i];
                m = fmaxf(m, c[i]);
            }
            float ssum = 0.f;
            #pragma unroll
            for (int i = 0; i < LL; ++i) ssum += __expf(c[i] - m);
            float anew = m + __logf(ssum) + emit;
            a = (mt && lane < LL) ? anew : a;
        }
        float f = (lane < LL) ? a + endT[lane] : -INFINITY;
        float m = f;
        #pragma unroll
        for (int off = 32; off; off >>= 1) m = fmaxf(m, __shfl_xor(m, off));
        float p = (lane < LL) ? __expf(f - m) : 0.f;
        #pragma unroll
        for (int off = 32; off; off >>= 1) p += __shfl_xor(p, off);
        if (lane == 0) denom[b] = m + __logf(p);
    }
}

// ---------------- K4: loss + one-hot logits ----------------
__global__ __launch_bounds__(256) void k_out(const float* __restrict__ num,
                                             const float* __restrict__ denom,
                                             const int* __restrict__ tagsW,
                                             const int* __restrict__ attn,
                                             float* __restrict__ out) {
    int gid = blockIdx.x * 256 + threadIdx.x;
    if ((int)blockIdx.x == (int)gridDim.x - 1 && threadIdx.x < 64) {
        float llh = num[threadIdx.x] - denom[threadIdx.x];
        #pragma unroll
        for (int off = 32; off; off >>= 1) llh += __shfl_xor(llh, off);
        if (threadIdx.x == 0) out[0] = -llh / (float)BB;
    }
    if (gid < BB * SS * LL) {
        int bt = gid / LL, l = gid % LL;
        int tag = tagsW[bt];
        int mk  = attn[bt];
        out[1 + gid] = (mk && tag == l) ? 1.f : 0.f;
    }
}

extern "C" void kernel_launch(void* const* d_in, const int* in_sizes, int n_in,
                              void* d_out, int out_size, void* d_ws, size_t ws_size,
                              hipStream_t stream) {
    const float* hidden = (const float*)d_in[0];
    const int*   attn   = (const int*)d_in[1];
    const int*   labels = (const int*)d_in[2];
    const float* W      = (const float*)d_in[3];
    const float* bias   = (const float*)d_in[4];
    const float* startT = (const float*)d_in[5];
    const float* endT   = (const float*)d_in[6];
    const float* trans  = (const float*)d_in[7];
    float* out = (float*)d_out;

    float* wsf   = (float*)d_ws;
    float* em    = wsf;                       // BB*SS*LL
    float* num   = wsf + (size_t)BB * SS * LL;
    float* denom = num + 64;
    int*   tags  = (int*)(denom + 64);        // BB*SS ints

    hipLaunchKernelGGL(k_emis, dim3(512), dim3(256), 0, stream, hidden, W, bias, em);
    hipLaunchKernelGGL(k_num,  dim3(BB),  dim3(SS),  0, stream, em, attn, labels,
                       startT, endT, trans, num);
    hipLaunchKernelGGL(k_scan, dim3(128), dim3(64),  0, stream, em, attn,
                       startT, endT, trans, denom, tags);
    int oh_blocks = (BB * SS * LL + 255) / 256;   // 2688 exactly
    hipLaunchKernelGGL(k_out,  dim3(oh_blocks + 1), dim3(256), 0, stream,
                       num, denom, tags, attn, out);
}

// Round 4
// 301.442 us; speedup vs baseline: 1.2703x; 1.2703x over previous
//
#include <hip/hip_runtime.h>
#include <math.h>

#define BB 64
#define SS 512
#define HH 768
#define LL 21
#define INFF __builtin_huge_valf()

__device__ inline float rlf(float v, int i) {
    return __int_as_float(__builtin_amdgcn_readlane(__float_as_int(v), i));
}
__device__ inline float mx3(float a, float b, float c) { return fmaxf(fmaxf(a, b), c); }
__device__ inline float wmax64(float v) {
    #pragma unroll
    for (int off = 32; off; off >>= 1) v = fmaxf(v, __shfl_xor(v, off));
    return v;
}

// ---------------- K1: emissions = hidden @ W + b ----------------
// 1 wave / 64 rows per block. Hidden staged in 32-k subtiles to LDS (stride 33,
// conflict-free column reads). W streamed via uniform (scalar) loads -> SGPR FMA.
__global__ __launch_bounds__(64) void k_emis(const float* __restrict__ hidden,
                                             const float* __restrict__ W,
                                             const float* __restrict__ bias,
                                             float* __restrict__ em) {
    __shared__ float hs[64 * 33];
    int lane = threadIdx.x;
    int r0 = blockIdx.x * 64;

    float acc[21];
    #pragma unroll
    for (int l = 0; l < 21; ++l) acc[l] = 0.f;

    float4 ra[8], rb[8];

#define LOADT(DST, KS) do { \
    _Pragma("unroll") for (int i2 = 0; i2 < 8; ++i2) { \
        int f = i2 * 64 + lane; int rr = f >> 3; int c4 = f & 7; \
        DST[i2] = *reinterpret_cast<const float4*>(hidden + (size_t)(r0 + rr) * HH + (KS) * 32 + c4 * 4); \
    } } while (0)
#define STORET(SRC) do { \
    _Pragma("unroll") for (int i2 = 0; i2 < 8; ++i2) { \
        int f = i2 * 64 + lane; int rr = f >> 3; int c4 = f & 7; \
        int base = rr * 33 + c4 * 4; \
        hs[base] = SRC[i2].x; hs[base + 1] = SRC[i2].y; \
        hs[base + 2] = SRC[i2].z; hs[base + 3] = SRC[i2].w; \
    } } while (0)
#define COMPUTET(KS) do { \
    _Pragma("unroll 4") for (int k = 0; k < 32; ++k) { \
        float hv = hs[lane * 33 + k]; \
        const float* Wr = W + ((KS) * 32 + k) * LL; \
        _Pragma("unroll") for (int l = 0; l < 21; ++l) acc[l] = fmaf(hv, Wr[l], acc[l]); \
    } } while (0)

    LOADT(ra, 0);
    for (int ks2 = 0; ks2 < 12; ++ks2) {
        int ksA = 2 * ks2, ksB = 2 * ks2 + 1;
        STORET(ra);
        LOADT(rb, ksB);
        COMPUTET(ksA);
        STORET(rb);
        if (ks2 < 11) LOADT(ra, ksA + 2);
        COMPUTET(ksB);
    }

    size_t rowg = (size_t)(r0 + lane);
    #pragma unroll
    for (int l = 0; l < 21; ++l) em[rowg * LL + l] = acc[l] + bias[l];
#undef LOADT
#undef STORET
#undef COMPUTET
}

// ---------------- K2: CRF numerator per batch ----------------
__global__ __launch_bounds__(512) void k_num(const float* __restrict__ em,
                                             const int* __restrict__ attn,
                                             const int* __restrict__ labels,
                                             const float* __restrict__ startT,
                                             const float* __restrict__ endT,
                                             const float* __restrict__ trans,
                                             float* __restrict__ num) {
    int b = blockIdx.x, t = threadIdx.x;
    __shared__ int   stag[SS];
    __shared__ float sred[SS];
    __shared__ int   scnt[SS];

    int lab = labels[b * SS + t];
    int mk  = attn[b * SS + t];
    int tag = (lab < 0) ? 0 : lab;
    if (t == 0) tag = 0;
    int valid = (mk != 0 && lab >= 0) ? 1 : 0;
    if (t == 0) valid = 1;
    stag[t] = tag;
    __syncthreads();

    float term = 0.f;
    if (t > 0 && valid) {
        int pt = stag[t - 1];
        term = trans[pt * LL + tag] + em[((size_t)b * SS + t) * LL + tag];
    }
    sred[t] = term;
    scnt[t] = valid;
    __syncthreads();
    for (int off = 256; off; off >>= 1) {
        if (t < off) { sred[t] += sred[t + off]; scnt[t] += scnt[t + off]; }
        __syncthreads();
    }
    if (t == 0) {
        int cnt   = scnt[0];
        int lastt = stag[cnt - 1];
        int t0    = stag[0];
        num[b] = startT[t0] + em[(size_t)b * SS * LL + t0] + endT[lastt] + sred[0];
    }
}

// ---------------- K3: Viterbi (blocks 0..63) + exp-trick LSE scan (64..127) ----
__global__ __launch_bounds__(64) void k_scan(const float* __restrict__ em,
                                             const int* __restrict__ attn,
                                             const float* __restrict__ startT,
                                             const float* __restrict__ endT,
                                             const float* __restrict__ trans,
                                             float* __restrict__ denom,
                                             int* __restrict__ tagsOut) {
    __shared__ unsigned char hh[SS * 24];     // hh[t*24+s]: masked predecessor map
    __shared__ unsigned char mapL[64 * 32];   // backtrack segment maps

    int lane = threadIdx.x;
    int b = blockIdx.x & 63;
    bool isVit = blockIdx.x < 64;
    bool act = lane < 21;
    int jj = act ? lane : 20;

    const float* emb = em + (size_t)b * SS * LL;
    const int* mrow = attn + b * SS;

    float eA[16], eB[16], eC[16], eD[16];

#define LOADC(EARR, H) do { \
    _Pragma("unroll") for (int c2 = 0; c2 < 16; ++c2) \
        (EARR)[c2] = emb[(q * 64 + (H) * 16 + c2) * LL + jj]; \
    } while (0)

    if (isVit) {
        float Tcol[21];
        #pragma unroll
        for (int i = 0; i < 21; ++i) Tcol[i] = act ? trans[i * LL + lane] : 0.f;
        float a = act ? (startT[lane] + emb[lane]) : -INFF;

#define VSTEP(EARR, C, H) do { \
    int t = q * 64 + (H) * 16 + (C); \
    if (t >= 1) { \
        float cc[21]; \
        _Pragma("unroll") for (int i = 0; i < 21; ++i) cc[i] = rlf(a, i) + Tcol[i]; \
        float m0 = mx3(cc[0], cc[1], cc[2]);   float m1 = mx3(cc[3], cc[4], cc[5]); \
        float m2 = mx3(cc[6], cc[7], cc[8]);   float m3 = mx3(cc[9], cc[10], cc[11]); \
        float m4 = mx3(cc[12], cc[13], cc[14]); float m5 = mx3(cc[15], cc[16], cc[17]); \
        float m6 = mx3(cc[18], cc[19], cc[20]); \
        float best = mx3(mx3(m0, m1, m2), mx3(m3, m4, m5), m6); \
        int bi = 20; \
        _Pragma("unroll") for (int i = 19; i >= 0; --i) bi = (cc[i] == best) ? i : bi; \
        bool mt = ((mm >> (t & 63)) & 1ull) != 0; \
        if (act) hh[t * 24 + lane] = (unsigned char)(mt ? bi : lane); \
        float anew = best + (EARR)[C]; \
        a = (mt && act) ? anew : a; \
    } } while (0)
#define VCHUNK(EARR, H) do { \
    _Pragma("unroll") for (int c = 0; c < 16; ++c) VSTEP(EARR, c, H); \
    } while (0)

        for (int q = 0; q < 8; ++q) {
            int mk = mrow[q * 64 + lane];
            unsigned long long mm = __ballot(mk != 0);
            LOADC(eA, 0); LOADC(eB, 1);
            VCHUNK(eA, 0); LOADC(eC, 2);
            VCHUNK(eB, 1); LOADC(eD, 3);
            VCHUNK(eC, 2);
            VCHUNK(eD, 3);
        }

        // final argmax (first max wins, exact float compare)
        float f = act ? (a + endT[lane]) : -INFF;
        float m = wmax64(f);
        unsigned long long msk = __ballot(f == m);
        int best_last = __ffsll(msk) - 1;

        // ---- segment-parallel backtrack ----
        int tlo = 8 * lane + 1;
        int thi = 8 * lane + 8; if (thi > 511) thi = 511;
        unsigned int BM[21];
        #pragma unroll
        for (int s = 0; s < 21; ++s) BM[s] = s;
        for (int k = 0; k < 8; ++k) {
            int t = thi - k;
            if (t >= tlo) {
                #pragma unroll
                for (int s = 0; s < 21; ++s) BM[s] = hh[t * 24 + BM[s]];
            }
        }
        #pragma unroll
        for (int s = 0; s < 21; ++s) mapL[lane * 32 + s] = (unsigned char)BM[s];

        #pragma unroll
        for (int kk = 1; kk < 64; kk <<= 1) {
            int p = lane + kk;
            bool vld = p < 64;
            int pp = vld ? p : 0;
            unsigned int P[21];
            #pragma unroll
            for (int s = 0; s < 21; ++s) {
                unsigned int v = mapL[pp * 32 + s];
                P[s] = vld ? v : (unsigned int)s;
            }
            unsigned int N[21];
            #pragma unroll
            for (int s = 0; s < 21; ++s) N[s] = mapL[lane * 32 + P[s]];
            #pragma unroll
            for (int s = 0; s < 21; ++s) mapL[lane * 32 + s] = (unsigned char)N[s];
        }

        int st8 = mapL[lane * 32 + best_last];          // state(8*lane)
        int nxt = __shfl(st8, lane + 1);
        int cur = (lane == 63) ? best_last : nxt;        // state(thi)
        for (int k = 0; k < 8; ++k) {
            int t = thi - k;
            if (t >= tlo) {
                tagsOut[b * SS + t] = cur;
                cur = hh[t * 24 + cur];
            }
        }
        if (lane == 0) tagsOut[b * SS] = cur;            // state(0)
#undef VSTEP
#undef VCHUNK
    } else {
        // LSE forward with exp(trans) trick
        float Ecol[21];
        #pragma unroll
        for (int i = 0; i < 21; ++i) Ecol[i] = act ? __expf(trans[i * LL + lane]) : 0.f;
        float a = act ? (startT[lane] + emb[lane]) : -INFF;
        float M = 0.f;

#define LSTEP(EARR, C, H) do { \
    int t = q * 64 + (H) * 16 + (C); \
    if (t >= 1) { \
        float x = __expf(a - M); \
        float S = rlf(x, 0) * Ecol[0]; \
        _Pragma("unroll") for (int i = 1; i < 21; ++i) S = fmaf(rlf(x, i), Ecol[i], S); \
        bool mt = ((mm >> (t & 63)) & 1ull) != 0; \
        float anew = M + __logf(S) + (EARR)[C]; \
        a = (mt && act) ? anew : a; \
    } } while (0)
#define LCHUNK(EARR, H) do { \
    M = wmax64(a); \
    _Pragma("unroll") for (int c = 0; c < 16; ++c) LSTEP(EARR, c, H); \
    } while (0)

        for (int q = 0; q < 8; ++q) {
            int mk = mrow[q * 64 + lane];
            unsigned long long mm = __ballot(mk != 0);
            LOADC(eA, 0); LOADC(eB, 1);
            LCHUNK(eA, 0); LOADC(eC, 2);
            LCHUNK(eB, 1); LOADC(eD, 3);
            LCHUNK(eC, 2);
            LCHUNK(eD, 3);
        }

        float f = act ? (a + endT[lane]) : -INFF;
        float m = wmax64(f);
        float p = act ? __expf(f - m) : 0.f;
        #pragma unroll
        for (int off = 32; off; off >>= 1) p += __shfl_xor(p, off);
        if (lane == 0) denom[b] = m + __logf(p);
#undef LSTEP
#undef LCHUNK
    }
#undef LOADC
}

// ---------------- K4: loss + one-hot logits ----------------
__global__ __launch_bounds__(256) void k_out(const float* __restrict__ num,
                                             const float* __restrict__ denom,
                                             const int* __restrict__ tagsW,
                                             const int* __restrict__ attn,
                                             float* __restrict__ out) {
    int gid = blockIdx.x * 256 + threadIdx.x;
    if ((int)blockIdx.x == (int)gridDim.x - 1 && threadIdx.x < 64) {
        float llh = num[threadIdx.x] - denom[threadIdx.x];
        #pragma unroll
        for (int off = 32; off; off >>= 1) llh += __shfl_xor(llh, off);
        if (threadIdx.x == 0) out[0] = -llh / (float)BB;
    }
    if (gid < BB * SS * LL) {
        int bt = gid / LL, l = gid % LL;
        int tag = tagsW[bt];
        int mk  = attn[bt];
        out[1 + gid] = (mk && tag == l) ? 1.f : 0.f;
    }
}

extern "C" void kernel_launch(void* const* d_in, const int* in_sizes, int n_in,
                              void* d_out, int out_size, void* d_ws, size_t ws_size,
                              hipStream_t stream) {
    const float* hidden = (const float*)d_in[0];
    const int*   attn   = (const int*)d_in[1];
    const int*   labels = (const int*)d_in[2];
    const float* W      = (const float*)d_in[3];
    const float* bias   = (const float*)d_in[4];
    const float* startT = (const float*)d_in[5];
    const float* endT   = (const float*)d_in[6];
    const float* trans  = (const float*)d_in[7];
    float* out = (float*)d_out;

    float* wsf   = (float*)d_ws;
    float* em    = wsf;                       // BB*SS*LL
    float* num   = wsf + (size_t)BB * SS * LL;
    float* denom = num + 64;
    int*   tags  = (int*)(denom + 64);        // BB*SS ints

    hipLaunchKernelGGL(k_emis, dim3(512), dim3(64),  0, stream, hidden, W, bias, em);
    hipLaunchKernelGGL(k_num,  dim3(BB),  dim3(SS),  0, stream, em, attn, labels,
                       startT, endT, trans, num);
    hipLaunchKernelGGL(k_scan, dim3(128), dim3(64),  0, stream, em, attn,
                       startT, endT, trans, denom, tags);
    int oh_blocks = (BB * SS * LL + 255) / 256;   // 2688 exactly
    hipLaunchKernelGGL(k_out,  dim3(oh_blocks + 1), dim3(256), 0, stream,
                       num, denom, tags, attn, out);
}

// Round 6
// 199.789 us; speedup vs baseline: 1.9167x; 1.5088x over previous
//
#include <hip/hip_runtime.h>
#include <math.h>

#define BB 64
#define SS 512
#define HH 768
#define LL 21
#define INFF __builtin_huge_valf()

__device__ inline float rlf(float v, int i) {
    return __int_as_float(__builtin_amdgcn_readlane(__float_as_int(v), i));
}
__device__ inline float mx3(float a, float b, float c) { return fmaxf(fmaxf(a, b), c); }
__device__ inline float wmax64(float v) {
    #pragma unroll
    for (int off = 32; off; off >>= 1) v = fmaxf(v, __shfl_xor(v, off));
    return v;
}
__device__ inline float rlmax21(float a) {
    float r0 = mx3(rlf(a, 0), rlf(a, 1), rlf(a, 2));
    float r1 = mx3(rlf(a, 3), rlf(a, 4), rlf(a, 5));
    float r2 = mx3(rlf(a, 6), rlf(a, 7), rlf(a, 8));
    float r3 = mx3(rlf(a, 9), rlf(a, 10), rlf(a, 11));
    float r4 = mx3(rlf(a, 12), rlf(a, 13), rlf(a, 14));
    float r5 = mx3(rlf(a, 15), rlf(a, 16), rlf(a, 17));
    float r6 = mx3(rlf(a, 18), rlf(a, 19), rlf(a, 20));
    return mx3(mx3(r0, r1, r2), mx3(r3, r4, r5), r6);
}

// ---------------- K1: emissions = hidden @ W + b ----------------
// 256 blocks x 256 thr; 128 rows/block; K split 2-ways across wave-pairs.
// Per 32-K chunk: h tiles staged coalesced->LDS (stride 33, 2-way-free reads),
// W chunk staged->LDS (uniform broadcast b128 reads). LDS combine of halves.
__global__ __launch_bounds__(256) void k_emis(const float* __restrict__ hidden,
                                              const float* __restrict__ W,
                                              const float* __restrict__ bias,
                                              float* __restrict__ em) {
    __shared__ float hA[128][33];     // 16896 B
    __shared__ float hB[128][33];     // 16896 B
    __shared__ float Wc[2][32][24];   // 6144 B (24-pad -> 16B-aligned rows)
    __shared__ float cmb[128][22];    // 11264 B  => 51200 B total

    int tid = threadIdx.x;
    int kh = tid >> 7;                // wave-uniform (waves 0-1: 0, waves 2-3: 1)
    int rloc = tid & 127;
    int r0 = blockIdx.x * 128;

    float acc[LL];
    #pragma unroll
    for (int l = 0; l < LL; ++l) acc[l] = 0.f;

    float (*hrow)[33] = kh ? hB : hA;

    for (int c = 0; c < 12; ++c) {
        __syncthreads();
        #pragma unroll
        for (int rep = 0; rep < 4; ++rep) {
            int f = rep * 256 + tid;      // 0..1023
            int rr = f >> 3, c4 = f & 7;
            const float* src = hidden + (size_t)(r0 + rr) * HH + c * 32 + c4 * 4;
            float4 va = *reinterpret_cast<const float4*>(src);
            float4 vb = *reinterpret_cast<const float4*>(src + 384);
            int b0 = c4 * 4;
            hA[rr][b0] = va.x; hA[rr][b0 + 1] = va.y; hA[rr][b0 + 2] = va.z; hA[rr][b0 + 3] = va.w;
            hB[rr][b0] = vb.x; hB[rr][b0 + 1] = vb.y; hB[rr][b0 + 2] = vb.z; hB[rr][b0 + 3] = vb.w;
        }
        for (int u = tid; u < 1344; u += 256) {
            int khu = (u >= 672) ? 1 : 0;
            int rem = u - khu * 672;
            int kk = rem / 21, ll = rem - kk * 21;
            Wc[khu][kk][ll] = W[(size_t)(khu * 384 + c * 32 + kk) * LL + ll];
        }
        __syncthreads();
        #pragma unroll 4
        for (int k = 0; k < 32; ++k) {
            float hv = hrow[rloc][k];
            const float* wp = &Wc[kh][k][0];
            float4 w0 = *reinterpret_cast<const float4*>(wp);
            float4 w1 = *reinterpret_cast<const float4*>(wp + 4);
            float4 w2 = *reinterpret_cast<const float4*>(wp + 8);
            float4 w3 = *reinterpret_cast<const float4*>(wp + 12);
            float4 w4 = *reinterpret_cast<const float4*>(wp + 16);
            float w20 = wp[20];
            acc[0]  = fmaf(hv, w0.x, acc[0]);  acc[1]  = fmaf(hv, w0.y, acc[1]);
            acc[2]  = fmaf(hv, w0.z, acc[2]);  acc[3]  = fmaf(hv, w0.w, acc[3]);
            acc[4]  = fmaf(hv, w1.x, acc[4]);  acc[5]  = fmaf(hv, w1.y, acc[5]);
            acc[6]  = fmaf(hv, w1.z, acc[6]);  acc[7]  = fmaf(hv, w1.w, acc[7]);
            acc[8]  = fmaf(hv, w2.x, acc[8]);  acc[9]  = fmaf(hv, w2.y, acc[9]);
            acc[10] = fmaf(hv, w2.z, acc[10]); acc[11] = fmaf(hv, w2.w, acc[11]);
            acc[12] = fmaf(hv, w3.x, acc[12]); acc[13] = fmaf(hv, w3.y, acc[13]);
            acc[14] = fmaf(hv, w3.z, acc[14]); acc[15] = fmaf(hv, w3.w, acc[15]);
            acc[16] = fmaf(hv, w4.x, acc[16]); acc[17] = fmaf(hv, w4.y, acc[17]);
            acc[18] = fmaf(hv, w4.z, acc[18]); acc[19] = fmaf(hv, w4.w, acc[19]);
            acc[20] = fmaf(hv, w20, acc[20]);
        }
    }
    __syncthreads();
    if (kh == 1) {
        #pragma unroll
        for (int l = 0; l < LL; ++l) cmb[rloc][l] = acc[l];
    }
    __syncthreads();
    if (kh == 0) {
        float* emr = em + (size_t)(r0 + rloc) * LL;
        #pragma unroll
        for (int l = 0; l < LL; ++l) emr[l] = acc[l] + cmb[rloc][l] + bias[l];
    }
}

// ---------------- K2: fused scan dispatch ----------------
// blocks 0-63:   Viterbi forward (value-only; exact f32 S[t] -> Sout)
// blocks 64-127: logsumexp forward (exp-trick, 3-chain FMA)
// blocks 128-191: CRF numerator (one wave)
// Emissions staged to LDS once (43KB) -> tiny VGPR footprint, no scratch.
__global__ __launch_bounds__(64) void k_scan(const float* __restrict__ em,
                                             const int* __restrict__ attn,
                                             const int* __restrict__ labels,
                                             const float* __restrict__ startT,
                                             const float* __restrict__ endT,
                                             const float* __restrict__ trans,
                                             float* __restrict__ num,
                                             float* __restrict__ denom,
                                             float* __restrict__ Sout) {
    __shared__ float eL[SS * LL];     // 43008 B
    int lane = threadIdx.x;
    int bid = blockIdx.x;
    bool act = lane < LL;
    int jj = act ? lane : (LL - 1);

    if (bid < 128) {
        int b = bid & 63;
        const float* emb = em + (size_t)b * SS * LL;
        const int* mrow = attn + b * SS;
        for (int f = lane; f < SS * LL / 4; f += 64) {
            *reinterpret_cast<float4*>(&eL[f * 4]) =
                *reinterpret_cast<const float4*>(emb + f * 4);
        }
        __syncthreads();

        if (bid < 64) {
            float Tcol[LL];
            #pragma unroll
            for (int i = 0; i < LL; ++i) Tcol[i] = trans[i * LL + jj];
            float a = act ? (startT[lane] + eL[lane]) : -INFF;
            float* Sb = Sout + (size_t)b * SS * LL;
            if (act) Sb[lane] = a;
            for (int q = 0; q < 8; ++q) {
                unsigned long long mm = __ballot(mrow[q * 64 + lane] != 0);
                int tbase = q * 64;
                #pragma unroll 16
                for (int tt = 0; tt < 64; ++tt) {
                    int t = tbase + tt;
                    if (t == 0) continue;
                    float emit = eL[t * LL + jj];
                    float cc[LL];
                    #pragma unroll
                    for (int i = 0; i < LL; ++i) cc[i] = rlf(a, i) + Tcol[i];
                    float m0 = mx3(cc[0], cc[1], cc[2]),   m1 = mx3(cc[3], cc[4], cc[5]);
                    float m2 = mx3(cc[6], cc[7], cc[8]),   m3 = mx3(cc[9], cc[10], cc[11]);
                    float m4 = mx3(cc[12], cc[13], cc[14]), m5 = mx3(cc[15], cc[16], cc[17]);
                    float m6 = mx3(cc[18], cc[19], cc[20]);
                    float best = mx3(mx3(m0, m1, m2), mx3(m3, m4, m5), m6);
                    bool mt = ((mm >> tt) & 1ull) != 0ull;
                    float anew = best + emit;
                    a = (mt && act) ? anew : a;
                    if (act) Sb[t * LL + lane] = a;
                }
            }
        } else {
            float Ecol[LL];
            #pragma unroll
            for (int i = 0; i < LL; ++i) Ecol[i] = __expf(trans[i * LL + jj]);
            float a = act ? (startT[lane] + eL[lane]) : -INFF;
            for (int q = 0; q < 8; ++q) {
                unsigned long long mm = __ballot(mrow[q * 64 + lane] != 0);
                #pragma unroll
                for (int h = 0; h < 4; ++h) {
                    float M = rlmax21(a);
                    #pragma unroll
                    for (int t2 = 0; t2 < 16; ++t2) {
                        int tt = h * 16 + t2;
                        int t = q * 64 + tt;
                        if (t == 0) continue;
                        float emit = eL[t * LL + jj];
                        float x = __expf(a - M);
                        float s0 = rlf(x, 0) * Ecol[0];
                        #pragma unroll
                        for (int i = 1; i < 7; ++i) s0 = fmaf(rlf(x, i), Ecol[i], s0);
                        float s1 = rlf(x, 7) * Ecol[7];
                        #pragma unroll
                        for (int i = 8; i < 14; ++i) s1 = fmaf(rlf(x, i), Ecol[i], s1);
                        float s2 = rlf(x, 14) * Ecol[14];
                        #pragma unroll
                        for (int i = 15; i < 21; ++i) s2 = fmaf(rlf(x, i), Ecol[i], s2);
                        float Ssum = (s0 + s1) + s2;
                        bool mt = ((mm >> tt) & 1ull) != 0ull;
                        float anew = M + __logf(Ssum) + emit;
                        a = (mt && act) ? anew : a;
                    }
                }
            }
            float f = act ? (a + endT[lane]) : -INFF;
            float m = wmax64(f);
            float p = act ? __expf(f - m) : 0.f;
            #pragma unroll
            for (int off = 32; off; off >>= 1) p += __shfl_xor(p, off);
            if (lane == 0) denom[b] = m + __logf(p);
        }
    } else {
        int b = bid - 128;
        const int* lrow = labels + b * SS;
        const int* arow = attn + b * SS;
        float psum = 0.f;
        int pcnt = 0;
        for (int s = 0; s < 8; ++s) {
            int t = s * 64 + lane;
            int lab = lrow[t];
            int mk = arow[t];
            int valid = (t == 0) ? 1 : ((mk != 0 && lab >= 0) ? 1 : 0);
            if (t >= 1 && valid) {
                int tag = (lab < 0) ? 0 : lab;
                int labp = lrow[t - 1];
                int tagp = (t == 1) ? 0 : ((labp < 0) ? 0 : labp);
                psum += trans[tagp * LL + tag] + em[((size_t)b * SS + t) * LL + tag];
            }
            pcnt += valid;
        }
        #pragma unroll
        for (int off = 32; off; off >>= 1) {
            psum += __shfl_xor(psum, off);
            pcnt += __shfl_xor(pcnt, off);
        }
        int ts = pcnt - 1;
        int labL = lrow[ts];
        int tagL = (ts == 0) ? 0 : ((labL < 0) ? 0 : labL);
        if (lane == 0)
            num[b] = startT[0] + em[(size_t)b * SS * LL + 0] + psum + endT[tagL];
    }
}

// ---------------- K3: backtrack (pred recompute from exact S + compose) ----
__global__ __launch_bounds__(256) void k_back(const float* __restrict__ S,
                                              const int* __restrict__ attn,
                                              const float* __restrict__ endT,
                                              const float* __restrict__ trans,
                                              int* __restrict__ tagsOut) {
    __shared__ unsigned char pred[SS * 24];   // 12288 B
    __shared__ unsigned char mapL[64 * 32];   // 2048 B
    __shared__ float Tl[441];                 // 1764 B
    int tid = threadIdx.x, b = blockIdx.x;
    const float* Sb = S + (size_t)b * SS * LL;
    for (int i = tid; i < 441; i += 256) Tl[i] = trans[i];
    __syncthreads();

    for (int u = tid; u < 511 * LL; u += 256) {
        int t = 1 + u / LL;
        int j = u - (u / LL) * LL;
        unsigned int pj = (unsigned int)j;
        if (attn[b * SS + t] != 0) {
            const float* Sp = Sb + (size_t)(t - 1) * LL;
            float bv = Sp[0] + Tl[j];
            unsigned int bi = 0;
            #pragma unroll
            for (int i = 1; i < LL; ++i) {
                float c = Sp[i] + Tl[i * LL + j];
                bool g = c > bv;            // strict > : first max wins
                bv = g ? c : bv;
                bi = g ? (unsigned int)i : bi;
            }
            pj = bi;
        }
        pred[t * 24 + j] = (unsigned char)pj;
    }
    __syncthreads();

    if (tid < 64) {
        int lane = tid;
        float f = (lane < LL) ? (Sb[511 * LL + lane] + endT[lane]) : -INFF;
        float m = wmax64(f);
        unsigned long long msk = __ballot(f == m);
        int best_last = __ffsll(msk) - 1;

        int tlo = 8 * lane + 1;
        int thi = 8 * lane + 8; if (thi > 511) thi = 511;
        unsigned int BM[LL];
        #pragma unroll
        for (int s = 0; s < LL; ++s) BM[s] = s;
        for (int k = 0; k < 8; ++k) {
            int t = thi - k;
            if (t >= tlo) {
                #pragma unroll
                for (int s = 0; s < LL; ++s) BM[s] = pred[t * 24 + BM[s]];
            }
        }
        #pragma unroll
        for (int s = 0; s < LL; ++s) mapL[lane * 32 + s] = (unsigned char)BM[s];

        #pragma unroll
        for (int kk = 1; kk < 64; kk <<= 1) {
            int p = lane + kk;
            bool vld = p < 64;
            int pp = vld ? p : 0;
            unsigned int P[LL];
            #pragma unroll
            for (int s = 0; s < LL; ++s) {
                unsigned int v = mapL[pp * 32 + s];
                P[s] = vld ? v : (unsigned int)s;
            }
            unsigned int N[LL];
            #pragma unroll
            for (int s = 0; s < LL; ++s) N[s] = mapL[lane * 32 + P[s]];
            #pragma unroll
            for (int s = 0; s < LL; ++s) mapL[lane * 32 + s] = (unsigned char)N[s];
        }

        int st8 = mapL[lane * 32 + best_last];
        int nxt = __shfl(st8, lane + 1);
        int cur = (lane == 63) ? best_last : nxt;
        for (int k = 0; k < 8; ++k) {
            int t = thi - k;
            if (t >= tlo) {
                tagsOut[b * SS + t] = cur;
                cur = pred[t * 24 + cur];
            }
        }
        if (lane == 0) tagsOut[b * SS] = cur;
    }
}

// ---------------- K4: loss + one-hot logits ----------------
__global__ __launch_bounds__(256) void k_out(const float* __restrict__ num,
                                             const float* __restrict__ denom,
                                             const int* __restrict__ tagsW,
                                             const int* __restrict__ attn,
                                             float* __restrict__ out) {
    int gid = blockIdx.x * 256 + threadIdx.x;
    if ((int)blockIdx.x == (int)gridDim.x - 1 && threadIdx.x < 64) {
        float llh = num[threadIdx.x] - denom[threadIdx.x];
        #pragma unroll
        for (int off = 32; off; off >>= 1) llh += __shfl_xor(llh, off);
        if (threadIdx.x == 0) out[0] = -llh / (float)BB;
    }
    if (gid < BB * SS * LL) {
        int bt = gid / LL, l = gid % LL;
        int tag = tagsW[bt];
        int mk  = attn[bt];
        out[1 + gid] = (mk && tag == l) ? 1.f : 0.f;
    }
}

extern "C" void kernel_launch(void* const* d_in, const int* in_sizes, int n_in,
                              void* d_out, int out_size, void* d_ws, size_t ws_size,
                              hipStream_t stream) {
    const float* hidden = (const float*)d_in[0];
    const int*   attn   = (const int*)d_in[1];
    const int*   labels = (const int*)d_in[2];
    const float* W      = (const float*)d_in[3];
    const float* bias   = (const float*)d_in[4];
    const float* startT = (const float*)d_in[5];
    const float* endT   = (const float*)d_in[6];
    const float* trans  = (const float*)d_in[7];
    float* out = (float*)d_out;

    float* wsf   = (float*)d_ws;
    float* em    = wsf;                       // BB*SS*LL
    float* num   = wsf + (size_t)BB * SS * LL;
    float* denom = num + 64;
    int*   tags  = (int*)(denom + 64);        // BB*SS ints
    float* Sbuf  = out + 1;                   // exact Viterbi scores; overwritten by k_out

    hipLaunchKernelGGL(k_emis, dim3(256), dim3(256), 0, stream, hidden, W, bias, em);
    hipLaunchKernelGGL(k_scan, dim3(192), dim3(64),  0, stream, em, attn, labels,
                       startT, endT, trans, num, denom, Sbuf);
    hipLaunchKernelGGL(k_back, dim3(64),  dim3(256), 0, stream, Sbuf, attn, endT, trans, tags);
    int oh_blocks = (BB * SS * LL + 255) / 256;   // 2688 exactly
    hipLaunchKernelGGL(k_out,  dim3(oh_blocks + 1), dim3(256), 0, stream,
                       num, denom, tags, attn, out);
}